// Round 1
// baseline (91.594 us; speedup 1.0000x reference)
//
#include <hip/hip_runtime.h>

#define ENT_GRID 16
#define ENT_DIM  64
#define EMB      1024   // ENT_GRID * ENT_DIM
#define LN_EPS   1e-5f

// One block per batch row. 256 threads; each thread produces 4 of the 1024
// outputs. Embedding row staged in LDS (broadcast reads). Fused LayerNorm.
__global__ __launch_bounds__(256, 4)
void wproj_ln_kernel(const float* __restrict__ ent_emb,
                     const int*   __restrict__ proj_ids,
                     const float* __restrict__ rel_tran,
                     const float* __restrict__ rel_bias,
                     const float* __restrict__ ln_w,
                     const float* __restrict__ ln_b,
                     float* __restrict__ out) {
    const int b = blockIdx.x;
    const int t = threadIdx.x;

    const long long r = (long long)proj_ids[b];
    const float* __restrict__ tran = rel_tran + (size_t)r * (ENT_DIM * ENT_GRID * ENT_GRID); // 16384 f
    const float* __restrict__ bias = rel_bias + (size_t)r * (ENT_DIM * ENT_GRID);            // 1024 f
    const float* __restrict__ e    = ent_emb  + (size_t)b * EMB;

    __shared__ float se[EMB];          // 4 KiB embedding row
    __shared__ float wsum[4], wsq[4];  // per-wave partials

    // Stage embedding row: 256 threads x float4 = 1024 floats, fully coalesced.
    reinterpret_cast<float4*>(se)[t] = reinterpret_cast<const float4*>(e)[t];
    __syncthreads();

    float x[4];
    float sum = 0.0f, sumsq = 0.0f;

#pragma unroll
    for (int k = 0; k < 4; ++k) {
        const int i = t + k * 256;     // output index in [0,1024)
        const int d = i >> 4;          // ent_dim slot
        // each thread reads its 16-float tran row contiguously (64 B)
        const float4* __restrict__ tr = reinterpret_cast<const float4*>(tran + (size_t)i * ENT_GRID);
        const float4* __restrict__ er = reinterpret_cast<const float4*>(se + d * ENT_GRID);
        float acc = bias[i];
#pragma unroll
        for (int q = 0; q < 4; ++q) {
            float4 a  = tr[q];
            float4 ev = er[q];         // broadcast within 16-lane groups, no bank conflict
            acc += a.x * ev.x + a.y * ev.y + a.z * ev.z + a.w * ev.w;
        }
        x[k]  = acc;
        sum   += acc;
        sumsq += acc * acc;
    }

    // wave64 butterfly reduce
#pragma unroll
    for (int off = 32; off > 0; off >>= 1) {
        sum   += __shfl_xor(sum, off, 64);
        sumsq += __shfl_xor(sumsq, off, 64);
    }
    const int wid = t >> 6;
    if ((t & 63) == 0) { wsum[wid] = sum; wsq[wid] = sumsq; }
    __syncthreads();

    const float tsum = wsum[0] + wsum[1] + wsum[2] + wsum[3];
    const float tsq  = wsq[0]  + wsq[1]  + wsq[2]  + wsq[3];
    const float mu   = tsum * (1.0f / (float)EMB);
    const float var  = tsq * (1.0f / (float)EMB) - mu * mu;
    const float rstd = rsqrtf(var + LN_EPS);

    float* __restrict__ ob = out + (size_t)b * EMB;
#pragma unroll
    for (int k = 0; k < 4; ++k) {
        const int i = t + k * 256;
        ob[i] = (x[k] - mu) * rstd * ln_w[i] + ln_b[i];
    }
}

extern "C" void kernel_launch(void* const* d_in, const int* in_sizes, int n_in,
                              void* d_out, int out_size, void* d_ws, size_t ws_size,
                              hipStream_t stream) {
    const float* ent_emb  = (const float*)d_in[0];
    const int*   proj_ids = (const int*)  d_in[1];
    const float* rel_tran = (const float*)d_in[2];
    const float* rel_bias = (const float*)d_in[3];
    const float* ln_w     = (const float*)d_in[4];
    const float* ln_b     = (const float*)d_in[5];
    float* out = (float*)d_out;

    const int B = in_sizes[1];  // 8192 batch rows (one proj_id each)

    wproj_ln_kernel<<<B, 256, 0, stream>>>(ent_emb, proj_ids, rel_tran, rel_bias,
                                           ln_w, ln_b, out);
}